// Round 1
// baseline (815.589 us; speedup 1.0000x reference)
//
#include <hip/hip_runtime.h>

#define COLS   32000
#define COLS4  8000      // COLS / 4
#define TPB    1024
#define NWAVES (TPB / 64)
#define VPT    8         // float4 loads per thread: 1024*8 = 8192 >= 8000

// Block-wide sum; returns the SAME bitwise value to all threads
// (final accumulation reads identical LDS values in identical order).
__device__ __forceinline__ float block_sum(float v, float* sred, int tid) {
    #pragma unroll
    for (int off = 32; off; off >>= 1) v += __shfl_xor(v, off, 64);
    __syncthreads();                       // protect prior readers of sred
    if ((tid & 63) == 0) sred[tid >> 6] = v;
    __syncthreads();
    float s = 0.f;
    #pragma unroll
    for (int i = 0; i < NWAVES; ++i) s += sred[i];
    return s;
}

__global__ __launch_bounds__(TPB) void entmax_kernel(const float* __restrict__ x,
                                                     float* __restrict__ out) {
    __shared__ float s_a[NWAVES];
    __shared__ float s_b[NWAVES];
    const int tid = threadIdx.x;
    const float4* __restrict__ xr = (const float4*)(x + (size_t)blockIdx.x * COLS);
    float4* __restrict__ yr = (float4*)(out + (size_t)blockIdx.x * COLS);

    // ---- load row into registers, track max/min of valid elements ----
    float z[4 * VPT];
    float vmax = -3.4e38f, vmin = 3.4e38f;
    #pragma unroll
    for (int k = 0; k < VPT; ++k) {
        const int c4 = tid + (k << 10);
        if (c4 < COLS4) {
            float4 v = xr[c4];
            z[4*k+0] = v.x; z[4*k+1] = v.y; z[4*k+2] = v.z; z[4*k+3] = v.w;
            vmax = fmaxf(vmax, fmaxf(fmaxf(v.x, v.y), fmaxf(v.z, v.w)));
            vmin = fminf(vmin, fminf(fminf(v.x, v.y), fminf(v.z, v.w)));
        } else {
            // finite sentinel: z becomes ~-1.5e38, clips to 0 in every sweep,
            // excluded from max/min, never stored
            z[4*k+0] = z[4*k+1] = z[4*k+2] = z[4*k+3] = -3.0e38f;
        }
    }

    // ---- block max/min reduction ----
    #pragma unroll
    for (int off = 32; off; off >>= 1) {
        vmax = fmaxf(vmax, __shfl_xor(vmax, off, 64));
        vmin = fminf(vmin, __shfl_xor(vmin, off, 64));
    }
    if ((tid & 63) == 0) { s_a[tid >> 6] = vmax; s_b[tid >> 6] = vmin; }
    __syncthreads();
    float rmax = s_a[0], rmin = s_b[0];
    #pragma unroll
    for (int i = 1; i < NWAVES; ++i) {
        rmax = fmaxf(rmax, s_a[i]);
        rmin = fminf(rmin, s_b[i]);
    }

    // z = (ALPHA-1) * x_shifted = 0.5f * (x - rowmax)   (exact *0.5)
    #pragma unroll
    for (int i = 0; i < 4 * VPT; ++i) z[i] = 0.5f * (z[i] - rmax);

    // tau_min = min(x_shifted) - 1;  min(x)-max == min(x-max) bitwise (monotone fp sub)
    const float a0 = (rmin - rmax) - 1.0f;
    // tau_max = max(x_shifted) == 0.0f exactly

    // ---- constraint at the first midpoint (replicates reference arithmetic) ----
    const float tau0 = (a0 + 0.0f) * 0.5f;
    float ls = 0.f;
    #pragma unroll
    for (int i = 0; i < 4 * VPT; ++i) {
        float t = fmaxf(z[i] - tau0, 0.f);
        ls = fmaf(t, t, ls);
    }
    const float g0 = block_sum(ls, s_a, tid) - 1.0f;   // block-uniform

    float tmin = a0, tmax = 0.0f;
    if (g0 > 4.0f) {
        // Reference's (inverted) bisection: after iter 0 the interval excludes
        // the root, g is strictly decreasing, so constraint > 0 at EVERY
        // iteration -> tmin never moves, tmax halves toward a0. Replay the
        // exact fp32 sequence; no further sweeps needed.
        #pragma unroll 1
        for (int i = 0; i < 50; ++i) tmax = (tmin + tmax) * 0.5f;
    } else {
        // Rare/ambiguous row: faithful 50-iteration bisection on register data.
        for (int i = 0; i < 50; ++i) {
            const float tau = (tmin + tmax) * 0.5f;
            float p = 0.f;
            #pragma unroll
            for (int j = 0; j < 4 * VPT; ++j) {
                float t = fmaxf(z[j] - tau, 0.f);
                p = fmaf(t, t, p);
            }
            const float cons = block_sum(p, s_a, tid) - 1.0f;
            if (cons < 0.f) tmin = tau;
            if (cons > 0.f) tmax = tau;
        }
    }
    const float tau = (tmin + tmax) * 0.5f;

    // ---- final y, sum, normalize, store ----
    float lsum = 0.f;
    #pragma unroll
    for (int i = 0; i < 4 * VPT; ++i) {
        float t = fmaxf(z[i] - tau, 0.f);
        t = t * t;
        z[i] = t;
        lsum += t;
    }
    const float S = block_sum(lsum, s_b, tid);
    const float inv = 1.0f / (S + 1e-12f);

    #pragma unroll
    for (int k = 0; k < VPT; ++k) {
        const int c4 = tid + (k << 10);
        if (c4 < COLS4) {
            float4 o;
            o.x = z[4*k+0] * inv;
            o.y = z[4*k+1] * inv;
            o.z = z[4*k+2] * inv;
            o.w = z[4*k+3] * inv;
            yr[c4] = o;
        }
    }
}

extern "C" void kernel_launch(void* const* d_in, const int* in_sizes, int n_in,
                              void* d_out, int out_size, void* d_ws, size_t ws_size,
                              hipStream_t stream) {
    const float* x = (const float*)d_in[0];
    float* out = (float*)d_out;
    const int rows = in_sizes[0] / COLS;   // 4096
    entmax_kernel<<<dim3(rows), dim3(TPB), 0, stream>>>(x, out);
}